// Round 1
// baseline (426.672 us; speedup 1.0000x reference)
//
#include <hip/hip_runtime.h>
#include <hip/hip_bf16.h>
#include <stdint.h>
#include <string.h>

#define NN 40000
#define NE 640000
#define D  128
#define NL 4
#define EPSV 1e-6f

typedef __attribute__((ext_vector_type(8))) short          s16x8;
typedef __attribute__((ext_vector_type(8))) unsigned short u16x8;
typedef __attribute__((ext_vector_type(4))) float          f32x4;

static __device__ __forceinline__ unsigned short f2b_bits(float f) {
  uint32_t u = __float_as_uint(f);
  uint32_t r = (u + 0x7fffu + ((u >> 16) & 1u)) >> 16;   // RNE
  return (unsigned short)r;
}
static __device__ __forceinline__ float blo(uint32_t p) { return __uint_as_float(p << 16); }
static __device__ __forceinline__ float bhi(uint32_t p) { return __uint_as_float(p & 0xffff0000u); }

// ---------------- weight prep: fp32 -> bf16 bits ----------------
__global__ void k_prep(const float* __restrict__ Wc, const float* __restrict__ Wh,
                       unsigned short* __restrict__ wcb, unsigned short* __restrict__ whb) {
  int i = blockIdx.x * 256 + threadIdx.x;
  if (i < NL * D * D) {
    wcb[i] = f2b_bits(Wc[i]);
    whb[i] = f2b_bits(Wh[i]);
  }
}

// ---------------- CSR build ----------------
__global__ void k_count(const int* __restrict__ e, int* __restrict__ deg) {
  int i = blockIdx.x * 256 + threadIdx.x;
  if (i < NE) atomicAdd(&deg[e[2 * i + 1]], 1);
}

__global__ __launch_bounds__(1024) void k_scan(const int* __restrict__ deg,
                                               int* __restrict__ rs, int n) {
  __shared__ int buf[1024];
  __shared__ int carry_s;
  int t = threadIdx.x;
  if (t == 0) { carry_s = 0; rs[0] = 0; }
  __syncthreads();
  for (int base = 0; base < n; base += 1024) {
    int i = base + t;
    int v = (i < n) ? deg[i] : 0;
    buf[t] = v;
    __syncthreads();
    for (int off = 1; off < 1024; off <<= 1) {
      int add = (t >= off) ? buf[t - off] : 0;
      __syncthreads();
      buf[t] += add;
      __syncthreads();
    }
    int incl = buf[t] + carry_s;
    if (i < n) rs[i + 1] = incl;
    __syncthreads();                 // everyone done reading carry_s
    if (t == 1023) carry_s = carry_s + buf[1023];
    __syncthreads();
  }
}

__global__ void k_fill(const int* __restrict__ e, const int* __restrict__ rs,
                       int* __restrict__ cursor, int* __restrict__ csr) {
  int i = blockIdx.x * 256 + threadIdx.x;
  if (i < NE) {
    int s = e[2 * i + 0];
    int d = e[2 * i + 1];
    int p = atomicAdd(&cursor[d], 1);
    csr[rs[d] + p] = s;
  }
}

// ---------------- KB: gather-max + residual + rmsnorm ----------------
// one wave per node; lane owns dims {2*lane, 2*lane+1}
__global__ __launch_bounds__(256) void k_gather_norm(
    const uint32_t* __restrict__ tp,      // t as packed bf16x2: [node][64]
    const float* __restrict__ hin,
    const float* __restrict__ g, const float* __restrict__ bg,
    const int* __restrict__ rs, const int* __restrict__ csr,
    float* __restrict__ hout) {
  int wave = threadIdx.x >> 6, lane = threadIdx.x & 63;
  int n = blockIdx.x * 4 + wave;
  int r0 = rs[n], r1 = rs[n + 1];
  float m0 = 0.f, m1 = 0.f;
  int i = r0;
  for (; i + 4 <= r1; i += 4) {
    int s0 = csr[i], s1 = csr[i + 1], s2 = csr[i + 2], s3 = csr[i + 3];
    uint32_t p0 = tp[s0 * 64 + lane];
    uint32_t p1 = tp[s1 * 64 + lane];
    uint32_t p2 = tp[s2 * 64 + lane];
    uint32_t p3 = tp[s3 * 64 + lane];
    m0 = fmaxf(fmaxf(m0, blo(p0)), fmaxf(blo(p1), fmaxf(blo(p2), blo(p3))));
    m1 = fmaxf(fmaxf(m1, bhi(p0)), fmaxf(bhi(p1), fmaxf(bhi(p2), bhi(p3))));
  }
  for (; i < r1; ++i) {
    uint32_t p = tp[csr[i] * 64 + lane];
    m0 = fmaxf(m0, blo(p));
    m1 = fmaxf(m1, bhi(p));
  }
  int d0 = lane * 2;
  float2 hv = *(const float2*)(hin + (size_t)n * D + d0);
  float u0 = hv.x + m0, u1 = hv.y + m1;
  float ss = u0 * u0 + u1 * u1;
#pragma unroll
  for (int off = 32; off; off >>= 1) ss += __shfl_xor(ss, off);
  float rf = rsqrtf(ss * (1.f / D) + EPSV);
  float2 o;
  o.x = u0 * rf * g[d0] + bg[d0];
  o.y = u1 * rf * g[d0 + 1] + bg[d0 + 1];
  *(float2*)(hout + (size_t)n * D + d0) = o;
}

// ---------------- KA/KC: MFMA GEMM (out = relu(h @ W^T + b)) ----------------
// NORM==0: write bf16 t.  NORM==1: h2 = rmsnorm(hin + y)*g + bg -> fp32 hout.
template <int NORM>
__global__ __launch_bounds__(256) void k_gemm(
    const float* __restrict__ hin,          // [NN, D] fp32
    const unsigned short* __restrict__ Wb,  // [D, D] bf16 bits (row o, k contiguous)
    const float* __restrict__ bias,         // [D]
    const float* __restrict__ g, const float* __restrict__ bg,
    unsigned short* __restrict__ tout,      // NORM==0
    float* __restrict__ hout) {             // NORM==1
  __shared__ float lds[4][16][D];
  int wave = threadIdx.x >> 6, lane = threadIdx.x & 63;
  int rowbase = (blockIdx.x * 4 + wave) * 16;
  int c15 = lane & 15, grp = lane >> 4;

  // A fragments: lane holds row (lane&15), k = ks*32 + (lane>>4)*8 .. +7
  s16x8 a[4];
  {
    const float* hp = hin + (size_t)(rowbase + c15) * D;
#pragma unroll
    for (int ks = 0; ks < 4; ++ks) {
      int k0 = ks * 32 + grp * 8;
      f32x4 x0 = *(const f32x4*)(hp + k0);
      f32x4 x1 = *(const f32x4*)(hp + k0 + 4);
      u16x8 av;
      av[0] = f2b_bits(x0[0]); av[1] = f2b_bits(x0[1]);
      av[2] = f2b_bits(x0[2]); av[3] = f2b_bits(x0[3]);
      av[4] = f2b_bits(x1[0]); av[5] = f2b_bits(x1[1]);
      av[6] = f2b_bits(x1[2]); av[7] = f2b_bits(x1[3]);
      a[ks] = __builtin_bit_cast(s16x8, av);
    }
  }

  f32x4 acc[8];
#pragma unroll
  for (int ct = 0; ct < 8; ++ct) { f32x4 z = {0.f, 0.f, 0.f, 0.f}; acc[ct] = z; }

#pragma unroll
  for (int ct = 0; ct < 8; ++ct) {
    const unsigned short* wp = Wb + (size_t)(ct * 16 + c15) * D;
#pragma unroll
    for (int ks = 0; ks < 4; ++ks) {
      int k0 = ks * 32 + grp * 8;
      s16x8 b = *(const s16x8*)(wp + k0);
      acc[ct] = __builtin_amdgcn_mfma_f32_16x16x32_bf16(a[ks], b, acc[ct], 0, 0, 0);
    }
  }

  // epilogue: bias + relu -> LDS (C layout: col = lane&15, row = grp*4+reg)
#pragma unroll
  for (int ct = 0; ct < 8; ++ct) {
    int col = ct * 16 + c15;
    float bv = bias[col];
#pragma unroll
    for (int r = 0; r < 4; ++r) {
      float v = acc[ct][r] + bv;
      lds[wave][grp * 4 + r][col] = fmaxf(v, 0.f);
    }
  }
  __syncthreads();

  if (NORM == 0) {
    // coalesced bf16 store of the 16x128 tile
#pragma unroll
    for (int it = 0; it < 4; ++it) {
      int idx = it * 512 + lane * 8;
      int r = idx >> 7, c = idx & 127;
      const float* lp = &lds[wave][r][c];
      f32x4 v0 = *(const f32x4*)lp;
      f32x4 v1 = *(const f32x4*)(lp + 4);
      u16x8 ov;
      ov[0] = f2b_bits(v0[0]); ov[1] = f2b_bits(v0[1]);
      ov[2] = f2b_bits(v0[2]); ov[3] = f2b_bits(v0[3]);
      ov[4] = f2b_bits(v1[0]); ov[5] = f2b_bits(v1[1]);
      ov[6] = f2b_bits(v1[2]); ov[7] = f2b_bits(v1[3]);
      *(u16x8*)(tout + (size_t)(rowbase + r) * D + c) = ov;
    }
  } else {
    int d0 = lane * 2;
    float g0 = g[d0], g1 = g[d0 + 1], b0 = bg[d0], b1 = bg[d0 + 1];
    for (int r = 0; r < 16; ++r) {
      float y0 = lds[wave][r][d0];
      float y1 = lds[wave][r][d0 + 1];
      float2 hv = *(const float2*)(hin + (size_t)(rowbase + r) * D + d0);
      float u0 = hv.x + y0, u1 = hv.y + y1;
      float ss = u0 * u0 + u1 * u1;
#pragma unroll
      for (int off = 32; off; off >>= 1) ss += __shfl_xor(ss, off);
      float rf = rsqrtf(ss * (1.f / D) + EPSV);
      float2 o;
      o.x = u0 * rf * g0 + b0;
      o.y = u1 * rf * g1 + b1;
      *(float2*)(hout + (size_t)(rowbase + r) * D + d0) = o;
    }
  }
}

// ---------------- launch ----------------
extern "C" void kernel_launch(void* const* d_in, const int* in_sizes, int n_in,
                              void* d_out, int out_size, void* d_ws, size_t ws_size,
                              hipStream_t stream) {
  (void)in_sizes; (void)n_in; (void)out_size; (void)ws_size;
  const float* x   = (const float*)d_in[0];
  const int*   e   = (const int*)d_in[1];
  const float* Wc  = (const float*)d_in[2];
  const float* bc  = (const float*)d_in[3];
  const float* gc  = (const float*)d_in[4];
  const float* bgc = (const float*)d_in[5];
  const float* Wh  = (const float*)d_in[6];
  const float* bh  = (const float*)d_in[7];
  const float* gh  = (const float*)d_in[8];
  const float* bgh = (const float*)d_in[9];
  float* out = (float*)d_out;

  char* base = (char*)d_ws;
  unsigned short* t   = (unsigned short*)(base + 0);          // 10,240,000 B
  float*          hA  = (float*)(base + 10240000);            // 20,480,000 B
  float*          hB  = (float*)(base + 30720000);            // 20,480,000 B
  unsigned short* wcb = (unsigned short*)(base + 51200000);   //    131,072 B
  unsigned short* whb = (unsigned short*)(base + 51331072);   //    131,072 B
  int*            ibf = (int*)(base + 51462144);              //    160,000 B
  int*            rs  = (int*)(base + 51622400);              //    160,004 B
  int*            csr = (int*)(base + 51782656);              //  2,560,000 B

  k_prep<<<512, 256, 0, stream>>>(Wc, Wh, wcb, whb);
  hipMemsetAsync(ibf, 0, NN * sizeof(int), stream);
  k_count<<<2500, 256, 0, stream>>>(e, ibf);
  k_scan<<<1, 1024, 0, stream>>>(ibf, rs, NN);
  hipMemsetAsync(ibf, 0, NN * sizeof(int), stream);
  k_fill<<<2500, 256, 0, stream>>>(e, rs, ibf, csr);

  for (int l = 0; l < NL; ++l) {
    const float* hin = (l == 0) ? x : hA;
    k_gemm<0><<<625, 256, 0, stream>>>(hin, wcb + (size_t)l * D * D, bc + l * D,
                                       nullptr, nullptr, t, nullptr);
    k_gather_norm<<<10000, 256, 0, stream>>>((const uint32_t*)t, hin,
                                             gc + l * D, bgc + l * D, rs, csr, hB);
    float* hout = (l == NL - 1) ? out : hA;
    k_gemm<1><<<625, 256, 0, stream>>>(hB, whb + (size_t)l * D * D, bh + l * D,
                                       gh + l * D, bgh + l * D, nullptr, hout);
  }
}

// Round 2
// 361.541 us; speedup vs baseline: 1.1801x; 1.1801x over previous
//
#include <hip/hip_runtime.h>
#include <hip/hip_bf16.h>
#include <stdint.h>
#include <string.h>

#define NN 40000
#define NE 640000
#define D  128
#define NL 4
#define EPSV 1e-6f

typedef __attribute__((ext_vector_type(8))) short          s16x8;
typedef __attribute__((ext_vector_type(8))) unsigned short u16x8;
typedef __attribute__((ext_vector_type(4))) float          f32x4;

static __device__ __forceinline__ unsigned short f2b_bits(float f) {
  uint32_t u = __float_as_uint(f);
  uint32_t r = (u + 0x7fffu + ((u >> 16) & 1u)) >> 16;   // RNE
  return (unsigned short)r;
}
static __device__ __forceinline__ float blo(uint32_t p) { return __uint_as_float(p << 16); }
static __device__ __forceinline__ float bhi(uint32_t p) { return __uint_as_float(p & 0xffff0000u); }

// ---------------- weight prep: fp32 -> bf16 bits ----------------
__global__ void k_prep(const float* __restrict__ Wc, const float* __restrict__ Wh,
                       unsigned short* __restrict__ wcb, unsigned short* __restrict__ whb) {
  int i = blockIdx.x * 256 + threadIdx.x;
  if (i < NL * D * D) {
    wcb[i] = f2b_bits(Wc[i]);
    whb[i] = f2b_bits(Wh[i]);
  }
}

// ---------------- CSR build (scan-free) ----------------
__global__ void k_count(const int* __restrict__ e, int* __restrict__ deg) {
  int i = blockIdx.x * 256 + threadIdx.x;
  if (i < NE) atomicAdd(&deg[e[2 * i + 1]], 1);
}

// rs[i] = chunk base for node i (arbitrary order; max is placement-independent)
__global__ void k_alloc(const int* __restrict__ deg, int* __restrict__ total,
                        int* __restrict__ rs) {
  int i = blockIdx.x * 256 + threadIdx.x;
  if (i < NN) rs[i] = atomicAdd(total, deg[i]);
}

__global__ void k_fill(const int* __restrict__ e, const int* __restrict__ rs,
                       int* __restrict__ cursor, int* __restrict__ csr) {
  int i = blockIdx.x * 256 + threadIdx.x;
  if (i < NE) {
    int s = e[2 * i + 0];
    int d = e[2 * i + 1];
    int p = atomicAdd(&cursor[d], 1);
    csr[rs[d] + p] = s;
  }
}

// ---------------- KB: gather-max + residual + rmsnorm ----------------
// one wave per node; lane owns dims {2*lane, 2*lane+1}
__global__ __launch_bounds__(256) void k_gather_norm(
    const uint32_t* __restrict__ tp,      // t as packed bf16x2: [node][64]
    const float* __restrict__ hin,
    const float* __restrict__ g, const float* __restrict__ bg,
    const int* __restrict__ rs, const int* __restrict__ deg,
    const int* __restrict__ csr,
    float* __restrict__ hout) {
  int wave = threadIdx.x >> 6, lane = threadIdx.x & 63;
  int n = blockIdx.x * 4 + wave;
  int r0 = rs[n], r1 = r0 + deg[n];
  float m0 = 0.f, m1 = 0.f;
  int i = r0;
  for (; i + 4 <= r1; i += 4) {
    int s0 = csr[i], s1 = csr[i + 1], s2 = csr[i + 2], s3 = csr[i + 3];
    uint32_t p0 = tp[s0 * 64 + lane];
    uint32_t p1 = tp[s1 * 64 + lane];
    uint32_t p2 = tp[s2 * 64 + lane];
    uint32_t p3 = tp[s3 * 64 + lane];
    m0 = fmaxf(fmaxf(m0, blo(p0)), fmaxf(blo(p1), fmaxf(blo(p2), blo(p3))));
    m1 = fmaxf(fmaxf(m1, bhi(p0)), fmaxf(bhi(p1), fmaxf(bhi(p2), bhi(p3))));
  }
  for (; i < r1; ++i) {
    uint32_t p = tp[csr[i] * 64 + lane];
    m0 = fmaxf(m0, blo(p));
    m1 = fmaxf(m1, bhi(p));
  }
  int d0 = lane * 2;
  float2 hv = *(const float2*)(hin + (size_t)n * D + d0);
  float u0 = hv.x + m0, u1 = hv.y + m1;
  float ss = u0 * u0 + u1 * u1;
#pragma unroll
  for (int off = 32; off; off >>= 1) ss += __shfl_xor(ss, off);
  float rf = rsqrtf(ss * (1.f / D) + EPSV);
  float2 o;
  o.x = u0 * rf * g[d0] + bg[d0];
  o.y = u1 * rf * g[d0 + 1] + bg[d0 + 1];
  *(float2*)(hout + (size_t)n * D + d0) = o;
}

// ---------------- layer-0 edge GEMM: t = relu(x @ Wc^T + bc) -> bf16 ----------------
__global__ __launch_bounds__(256) void k_gemm0(
    const float* __restrict__ hin,
    const unsigned short* __restrict__ Wb,
    const float* __restrict__ bias,
    unsigned short* __restrict__ tout) {
  __shared__ float lds[4][16][D];
  int wave = threadIdx.x >> 6, lane = threadIdx.x & 63;
  int rowbase = (blockIdx.x * 4 + wave) * 16;
  int c15 = lane & 15, grp = lane >> 4;

  s16x8 a[4];
  {
    const float* hp = hin + (size_t)(rowbase + c15) * D;
#pragma unroll
    for (int ks = 0; ks < 4; ++ks) {
      int k0 = ks * 32 + grp * 8;
      f32x4 x0 = *(const f32x4*)(hp + k0);
      f32x4 x1 = *(const f32x4*)(hp + k0 + 4);
      u16x8 av;
      av[0] = f2b_bits(x0[0]); av[1] = f2b_bits(x0[1]);
      av[2] = f2b_bits(x0[2]); av[3] = f2b_bits(x0[3]);
      av[4] = f2b_bits(x1[0]); av[5] = f2b_bits(x1[1]);
      av[6] = f2b_bits(x1[2]); av[7] = f2b_bits(x1[3]);
      a[ks] = __builtin_bit_cast(s16x8, av);
    }
  }

  f32x4 acc[8];
#pragma unroll
  for (int ct = 0; ct < 8; ++ct) { f32x4 z = {0.f, 0.f, 0.f, 0.f}; acc[ct] = z; }
#pragma unroll
  for (int ct = 0; ct < 8; ++ct) {
    const unsigned short* wp = Wb + (size_t)(ct * 16 + c15) * D;
#pragma unroll
    for (int ks = 0; ks < 4; ++ks) {
      s16x8 b = *(const s16x8*)(wp + ks * 32 + grp * 8);
      acc[ct] = __builtin_amdgcn_mfma_f32_16x16x32_bf16(a[ks], b, acc[ct], 0, 0, 0);
    }
  }
#pragma unroll
  for (int ct = 0; ct < 8; ++ct) {
    int col = ct * 16 + c15;
    float bv = bias[col];
#pragma unroll
    for (int r = 0; r < 4; ++r)
      lds[wave][grp * 4 + r][col] = fmaxf(acc[ct][r] + bv, 0.f);
  }
  __syncthreads();
#pragma unroll
  for (int it = 0; it < 4; ++it) {
    int idx = it * 512 + lane * 8;
    int r = idx >> 7, c = idx & 127;
    const float* lp = &lds[wave][r][c];
    f32x4 v0 = *(const f32x4*)lp;
    f32x4 v1 = *(const f32x4*)(lp + 4);
    u16x8 ov;
    ov[0] = f2b_bits(v0[0]); ov[1] = f2b_bits(v0[1]);
    ov[2] = f2b_bits(v0[2]); ov[3] = f2b_bits(v0[3]);
    ov[4] = f2b_bits(v1[0]); ov[5] = f2b_bits(v1[1]);
    ov[6] = f2b_bits(v1[2]); ov[7] = f2b_bits(v1[3]);
    *(u16x8*)(tout + (size_t)(rowbase + r) * D + c) = ov;
  }
}

// ---------------- fused: h2 = rmsnorm(hB + relu(hB@Wh^T+bh)); optionally
//                  t' = relu(h2 @ Wc'^T + bc') for the next layer ----------------
template <int WRITE_T>
__global__ __launch_bounds__(256) void k_fused(
    const float* __restrict__ hin,            // hB
    const unsigned short* __restrict__ Whb, const float* __restrict__ bh_v,
    const float* __restrict__ g, const float* __restrict__ bg,
    const unsigned short* __restrict__ Wcb, const float* __restrict__ bc_v,
    float* __restrict__ hout,
    unsigned short* __restrict__ tout) {
  __shared__ float u[4][16][132];             // +4 pad: conflict-free row reads
  int wave = threadIdx.x >> 6, lane = threadIdx.x & 63;
  int rowbase = (blockIdx.x * 4 + wave) * 16;
  int c15 = lane & 15, grp = lane >> 4;

  // A frags from global; stash fp32 tile in LDS for the residual
  s16x8 a[4];
  {
    const float* hp = hin + (size_t)(rowbase + c15) * D;
#pragma unroll
    for (int ks = 0; ks < 4; ++ks) {
      int k0 = ks * 32 + grp * 8;
      f32x4 x0 = *(const f32x4*)(hp + k0);
      f32x4 x1 = *(const f32x4*)(hp + k0 + 4);
      *(f32x4*)&u[wave][c15][k0]     = x0;
      *(f32x4*)&u[wave][c15][k0 + 4] = x1;
      u16x8 av;
      av[0] = f2b_bits(x0[0]); av[1] = f2b_bits(x0[1]);
      av[2] = f2b_bits(x0[2]); av[3] = f2b_bits(x0[3]);
      av[4] = f2b_bits(x1[0]); av[5] = f2b_bits(x1[1]);
      av[6] = f2b_bits(x1[2]); av[7] = f2b_bits(x1[3]);
      a[ks] = __builtin_bit_cast(s16x8, av);
    }
  }

  f32x4 acc[8];
#pragma unroll
  for (int ct = 0; ct < 8; ++ct) { f32x4 z = {0.f, 0.f, 0.f, 0.f}; acc[ct] = z; }
#pragma unroll
  for (int ct = 0; ct < 8; ++ct) {
    const unsigned short* wp = Whb + (size_t)(ct * 16 + c15) * D;
#pragma unroll
    for (int ks = 0; ks < 4; ++ks) {
      s16x8 b = *(const s16x8*)(wp + ks * 32 + grp * 8);
      acc[ct] = __builtin_amdgcn_mfma_f32_16x16x32_bf16(a[ks], b, acc[ct], 0, 0, 0);
    }
  }
  __syncthreads();

  // u += relu(acc + bias)
#pragma unroll
  for (int ct = 0; ct < 8; ++ct) {
    int col = ct * 16 + c15;
    float bv = bh_v[col];
#pragma unroll
    for (int r = 0; r < 4; ++r)
      u[wave][grp * 4 + r][col] += fmaxf(acc[ct][r] + bv, 0.f);
  }
  __syncthreads();

  // rmsnorm rows in LDS; write h2 to LDS + global
  {
    int d0 = lane * 2;
    float g0 = g[d0], g1 = g[d0 + 1], b0 = bg[d0], b1 = bg[d0 + 1];
    for (int r = 0; r < 16; ++r) {
      float u0 = u[wave][r][d0], u1 = u[wave][r][d0 + 1];
      float ss = u0 * u0 + u1 * u1;
#pragma unroll
      for (int off = 32; off; off >>= 1) ss += __shfl_xor(ss, off);
      float rf = rsqrtf(ss * (1.f / D) + EPSV);
      float o0 = u0 * rf * g0 + b0;
      float o1 = u1 * rf * g1 + b1;
      u[wave][r][d0] = o0;
      u[wave][r][d0 + 1] = o1;
      float2 o; o.x = o0; o.y = o1;
      *(float2*)(hout + (size_t)(rowbase + r) * D + d0) = o;
    }
  }

  if (WRITE_T) {
    __syncthreads();
    // A frags for next-layer edge GEMM, straight from LDS h2
    s16x8 a2[4];
#pragma unroll
    for (int ks = 0; ks < 4; ++ks) {
      int k0 = ks * 32 + grp * 8;
      f32x4 x0 = *(const f32x4*)&u[wave][c15][k0];
      f32x4 x1 = *(const f32x4*)&u[wave][c15][k0 + 4];
      u16x8 av;
      av[0] = f2b_bits(x0[0]); av[1] = f2b_bits(x0[1]);
      av[2] = f2b_bits(x0[2]); av[3] = f2b_bits(x0[3]);
      av[4] = f2b_bits(x1[0]); av[5] = f2b_bits(x1[1]);
      av[6] = f2b_bits(x1[2]); av[7] = f2b_bits(x1[3]);
      a2[ks] = __builtin_bit_cast(s16x8, av);
    }
    f32x4 acc2[8];
#pragma unroll
    for (int ct = 0; ct < 8; ++ct) { f32x4 z = {0.f, 0.f, 0.f, 0.f}; acc2[ct] = z; }
#pragma unroll
    for (int ct = 0; ct < 8; ++ct) {
      const unsigned short* wp = Wcb + (size_t)(ct * 16 + c15) * D;
#pragma unroll
      for (int ks = 0; ks < 4; ++ks) {
        s16x8 b = *(const s16x8*)(wp + ks * 32 + grp * 8);
        acc2[ct] = __builtin_amdgcn_mfma_f32_16x16x32_bf16(a2[ks], b, acc2[ct], 0, 0, 0);
      }
    }
    __syncthreads();
#pragma unroll
    for (int ct = 0; ct < 8; ++ct) {
      int col = ct * 16 + c15;
      float bv = bc_v[col];
#pragma unroll
      for (int r = 0; r < 4; ++r)
        u[wave][grp * 4 + r][col] = fmaxf(acc2[ct][r] + bv, 0.f);
    }
    __syncthreads();
#pragma unroll
    for (int it = 0; it < 4; ++it) {
      int idx = it * 512 + lane * 8;
      int r = idx >> 7, c = idx & 127;
      f32x4 v0 = *(const f32x4*)&u[wave][r][c];
      f32x4 v1 = *(const f32x4*)&u[wave][r][c + 4];
      u16x8 ov;
      ov[0] = f2b_bits(v0[0]); ov[1] = f2b_bits(v0[1]);
      ov[2] = f2b_bits(v0[2]); ov[3] = f2b_bits(v0[3]);
      ov[4] = f2b_bits(v1[0]); ov[5] = f2b_bits(v1[1]);
      ov[6] = f2b_bits(v1[2]); ov[7] = f2b_bits(v1[3]);
      *(u16x8*)(tout + (size_t)(rowbase + r) * D + c) = ov;
    }
  }
}

// ---------------- launch ----------------
extern "C" void kernel_launch(void* const* d_in, const int* in_sizes, int n_in,
                              void* d_out, int out_size, void* d_ws, size_t ws_size,
                              hipStream_t stream) {
  (void)in_sizes; (void)n_in; (void)out_size; (void)ws_size;
  const float* x   = (const float*)d_in[0];
  const int*   e   = (const int*)d_in[1];
  const float* Wc  = (const float*)d_in[2];
  const float* bc  = (const float*)d_in[3];
  const float* gc  = (const float*)d_in[4];
  const float* bgc = (const float*)d_in[5];
  const float* Wh  = (const float*)d_in[6];
  const float* bh  = (const float*)d_in[7];
  const float* gh  = (const float*)d_in[8];
  const float* bgh = (const float*)d_in[9];
  float* out = (float*)d_out;

  char* base = (char*)d_ws;
  unsigned short* t    = (unsigned short*)(base + 0);          // 10,240,000
  float*          hA   = (float*)(base + 10240000);            // 20,480,000
  float*          hB   = (float*)(base + 30720000);            // 20,480,000
  unsigned short* wcb  = (unsigned short*)(base + 51200000);   //    131,072
  unsigned short* whb  = (unsigned short*)(base + 51331072);   //    131,072
  int*            deg  = (int*)(base + 51462144);              //    160,000
  int*            cur  = (int*)(base + 51622144);              //    160,000
  int*            tot  = (int*)(base + 51782144);              //         64
  int*            rs   = (int*)(base + 51782208);              //    160,000
  int*            csr  = (int*)(base + 51942208);              //  2,560,000

  k_prep<<<512, 256, 0, stream>>>(Wc, Wh, wcb, whb);
  hipMemsetAsync(deg, 0, 2 * 160000 + 64, stream);   // deg | cur | tot
  k_count<<<2500, 256, 0, stream>>>(e, deg);
  k_alloc<<<157, 256, 0, stream>>>(deg, tot, rs);
  k_fill<<<2500, 256, 0, stream>>>(e, rs, cur, csr);

  // layer 0 edge GEMM on x
  k_gemm0<<<625, 256, 0, stream>>>(x, wcb, bc, t);

  for (int l = 0; l < NL; ++l) {
    const float* hin = (l == 0) ? x : hA;
    k_gather_norm<<<10000, 256, 0, stream>>>((const uint32_t*)t, hin,
                                             gc + l * D, bgc + l * D, rs, deg, csr, hB);
    if (l < NL - 1) {
      k_fused<1><<<625, 256, 0, stream>>>(hB, whb + (size_t)l * D * D, bh + l * D,
                                          gh + l * D, bgh + l * D,
                                          wcb + (size_t)(l + 1) * D * D, bc + (l + 1) * D,
                                          hA, t);
    } else {
      k_fused<0><<<625, 256, 0, stream>>>(hB, whb + (size_t)l * D * D, bh + l * D,
                                          gh + l * D, bgh + l * D,
                                          nullptr, nullptr, out, nullptr);
    }
  }
}